// Round 7
// baseline (107.085 us; speedup 1.0000x reference)
//
#include <hip/hip_runtime.h>

// AttentionNet N=128, a1=a2=64, f=2 — R7: fused single launch, full chip,
// latency-optimized sync. Grid 2N=256; pair (n, n+128) shares an XCD under
// the usual blockIdx%8 round-robin (perf heuristic only, correctness-safe).
// Per stage: m-values go straight to global (encoded m+2.0, exp==0x80 ->
// self-validating vs 0xAA poison/zeros); wave0 polls all 64 slots (own block
// included) -> one less barrier per stage, gather overlaps slow waves.
// Inner loop: p strided LDS (PAD=65, 2-way free), q via register + readlane,
// v_fma + v_rcp + add.

constexpr int A   = 64;
constexpr int PAD = 65;
constexpr float L2E  = 1.4426950408889634f;
constexpr float EPSF = 1e-6f;

__device__ __forceinline__ float bcast(float v, int srcLane) {
    return __int_as_float(__builtin_amdgcn_readlane(__float_as_int(v), srcLane));
}
__device__ __forceinline__ float rcpf(float v) { return __builtin_amdgcn_rcpf(v); }
__device__ __forceinline__ float ex2(float v)  { return __builtin_amdgcn_exp2f(v); }

// Spin until slot holds an encoded value (sign 0, exponent 128 <=> v in [2,4)).
__device__ __forceinline__ float poll_m(const float* __restrict__ p) {
    for (;;) {
        float f = __hip_atomic_load(p, __ATOMIC_RELAXED, __HIP_MEMORY_SCOPE_AGENT);
        unsigned u = __float_as_uint(f);
        if ((u >> 23) == 0x80u) return f - 2.0f;
        __builtin_amdgcn_s_sleep(1);
    }
}

// Reduce rows row0,row0+1 (lane <-> column j); lane0 stores encoded m to mg.
__device__ __forceinline__ void att2q(const float* __restrict__ prow,
                                      const float* __restrict__ qL,
                                      int row0, int lane,
                                      float* __restrict__ mg)   // [64] this n,stage
{
    const float qreg0 = qL[row0 * PAD + lane];          // conflict-free row reads
    const float qreg1 = qL[(row0 + 1) * PAD + lane];
    float acc0 = 0.f, acc1 = 0.f;
#pragma unroll 1
    for (int c = 0; c < 4; ++c) {
        float pk[16];
#pragma unroll
        for (int t = 0; t < 16; ++t) pk[t] = prow[c * 16 + t];
#pragma unroll
        for (int t = 0; t < 16; ++t) {
            const int k = c * 16 + t;                   // uniform -> readlane imm
            float q0 = bcast(qreg0, k);
            float q1 = bcast(qreg1, k);
            acc0 += rcpf(fmaf(pk[t], q0, 1.0f));
            acc1 += rcpf(fmaf(pk[t], q1, 1.0f));
        }
    }
    float s0 = acc0, m0 = acc0, s1 = acc1, m1 = acc1;
#pragma unroll
    for (int off = 1; off < 64; off <<= 1) {
        s0 += __shfl_xor(s0, off, 64);
        m0 = fmaxf(m0, __shfl_xor(m0, off, 64));
        s1 += __shfl_xor(s1, off, 64);
        m1 = fmaxf(m1, __shfl_xor(m1, off, 64));
    }
    if (lane == 0) {
        // acc = 64*c: mean_j c = s/4096, max_j c = m/64; encode +2.0.
        float v0 = (s0 * (1.0f / 4096.0f)) / (m0 * (1.0f / 64.0f) + EPSF);
        float v1 = (s1 * (1.0f / 4096.0f)) / (m1 * (1.0f / 64.0f) + EPSF);
        __hip_atomic_store(mg + row0,     v0 + 2.0f, __ATOMIC_RELAXED, __HIP_MEMORY_SCOPE_AGENT);
        __hip_atomic_store(mg + row0 + 1, v1 + 2.0f, __ATOMIC_RELAXED, __HIP_MEMORY_SCOPE_AGENT);
    }
}

__device__ __forceinline__ float softmax64(float m, float sharp, float th, bool last)
{
    float v = fmaxf(0.f, m * sharp + th);
    float mx = v;
#pragma unroll
    for (int off = 1; off < 64; off <<= 1) mx = fmaxf(mx, __shfl_xor(mx, off, 64));
    float e = __expf(v - mx);
    float s = e;
#pragma unroll
    for (int off = 1; off < 64; off <<= 1) s += __shfl_xor(s, off, 64);
    float r = e / s;
    if (!last) {
        float rm = r;
#pragma unroll
        for (int off = 1; off < 64; off <<= 1) rm = fmaxf(rm, __shfl_xor(rm, off, 64));
        r = r / (rm + EPSF);
    }
    return r;
}

__global__ __launch_bounds__(1024, 2)
void attn_half(const float* __restrict__ x,
               const float* __restrict__ fcW, const float* __restrict__ fcb,
               const float* __restrict__ p1W, const float* __restrict__ p1b,
               const float* __restrict__ p1s, const float* __restrict__ p1t,
               const float* __restrict__ p2W, const float* __restrict__ p2b,
               const float* __restrict__ p2s, const float* __restrict__ p2t,
               const float* __restrict__ oW,  const float* __restrict__ ob,
               const float* __restrict__ os,  const float* __restrict__ ot,
               float* __restrict__ mglob,     // [N][3][64]
               float* __restrict__ out)
{
    __shared__ float pL[A * PAD];
    __shared__ float qL[A * PAD];
    __shared__ float v1buf[A], v2buf[A];

    const int tid = threadIdx.x, lane = tid & 63, wv = tid >> 6;
    const int n = blockIdx.x & 127, half = blockIdx.x >> 7;   // pair shares XCD
    const int row0 = half * 32 + wv * 2;
    const int i = tid >> 4, j = (tid & 15) * 4;
    float* mg = mglob + (size_t)n * 3 * A;

    // ---- x loaded once; h0/h1 live in registers ----
    const float4* x0v = (const float4*)(x + (size_t)n * 2 * A * A);
    const float4* x1v = x0v + (A * A / 4);
    const float4 a = x0v[tid];
    const float4 c = x1v[tid];
    const float w00 = fcW[0], w01 = fcW[1], w10 = fcW[2], w11 = fcW[3];
    const float b0 = fcb[0], b1 = fcb[1];
    const float h0v[4] = { fmaxf(0.f, w00 * a.x + w01 * c.x + b0),
                           fmaxf(0.f, w00 * a.y + w01 * c.y + b0),
                           fmaxf(0.f, w00 * a.z + w01 * c.z + b0),
                           fmaxf(0.f, w00 * a.w + w01 * c.w + b0) };
    const float h1v[4] = { fmaxf(0.f, w10 * a.x + w11 * c.x + b1),
                           fmaxf(0.f, w10 * a.y + w11 * c.y + b1),
                           fmaxf(0.f, w10 * a.z + w11 * c.z + b1),
                           fmaxf(0.f, w10 * a.w + w11 * c.w + b1) };

    // ======== stage B: X = h0 (row-major) ========
    {
        const float W0 = p1W[0], W1 = p1W[1], bb = p1b[0];
#pragma unroll
        for (int t = 0; t < 4; ++t) {
            pL[i * PAD + j + t] = ex2(-L2E * (W0 * h0v[t] + bb));
            qL[i * PAD + j + t] = ex2(-L2E * (W1 * h0v[t]));
        }
    }
    __syncthreads();
    att2q(pL + lane * PAD, qL, row0, lane, mg);
    if (wv == 0) v1buf[lane] = softmax64(poll_m(mg + lane), p1s[0], p1t[0], false);
    __syncthreads();   // v1buf ready + all waves done reading B tiles

    // ======== stage C: X[r][k] = h1[k][r] * v1[k] (transposed store) ========
    {
        const float W0 = p2W[0], W1 = p2W[1], bb = p2b[0];
        const float sc = v1buf[i];
#pragma unroll
        for (int t = 0; t < 4; ++t) {
            float hv = h1v[t] * sc;
            pL[(j + t) * PAD + i] = ex2(-L2E * (W0 * hv + bb));
            qL[(j + t) * PAD + i] = ex2(-L2E * (W1 * hv));
        }
    }
    __syncthreads();
    att2q(pL + lane * PAD, qL, row0, lane, mg + A);
    if (wv == 0) v2buf[lane] = softmax64(poll_m(mg + A + lane), p2s[0], p2t[0], false);
    __syncthreads();   // v2buf ready + all waves done reading C tiles

    // ======== stage D: X = h0 * v1[i] * v2[j] (row-major) ========
    {
        const float W0 = oW[0], W1 = oW[1], bb = ob[0];
        const float sc = v1buf[i];
        const float4 v2q = *(const float4*)&v2buf[j];
        const float v2a[4] = { v2q.x, v2q.y, v2q.z, v2q.w };
#pragma unroll
        for (int t = 0; t < 4; ++t) {
            float hv = h0v[t] * sc * v2a[t];
            pL[i * PAD + j + t] = ex2(-L2E * (W0 * hv + bb));
            qL[i * PAD + j + t] = ex2(-L2E * (W1 * hv));
        }
    }
    __syncthreads();
    att2q(pL + lane * PAD, qL, row0, lane, mg + 2 * A);

    // ======== final softmax (is_last): half0/wave0 writes all 64 outputs ====
    if (half == 0 && wv == 0) {
        float r = softmax64(poll_m(mg + 2 * A + lane), os[0], ot[0], true);
        out[(size_t)n * A + lane] = r;
    }
}

extern "C" void kernel_launch(void* const* d_in, const int* in_sizes, int n_in,
                              void* d_out, int out_size, void* d_ws, size_t ws_size,
                              hipStream_t stream)
{
    (void)n_in; (void)out_size; (void)ws_size;
    const float* x   = (const float*)d_in[0];
    const float* fcW = (const float*)d_in[1];
    const float* fcb = (const float*)d_in[2];
    const float* p1W = (const float*)d_in[3];
    const float* p1b = (const float*)d_in[4];
    const float* p1s = (const float*)d_in[5];
    const float* p1t = (const float*)d_in[6];
    const float* p2W = (const float*)d_in[7];
    const float* p2b = (const float*)d_in[8];
    const float* p2s = (const float*)d_in[9];
    const float* p2t = (const float*)d_in[10];
    const float* oW  = (const float*)d_in[11];
    const float* ob  = (const float*)d_in[12];
    const float* os  = (const float*)d_in[13];
    const float* ot  = (const float*)d_in[14];
    float* out = (float*)d_out;

    const int N = in_sizes[0] / (2 * A * A);   // 128
    float* mglob = (float*)d_ws;               // [N][3][64]

    attn_half<<<2 * N, 1024, 0, stream>>>(x, fcW, fcb,
                                          p1W, p1b, p1s, p1t,
                                          p2W, p2b, p2s, p2t,
                                          oW, ob, os, ot, mglob, out);
}

// Round 8
// 103.676 us; speedup vs baseline: 1.0329x; 1.0329x over previous
//
#include <hip/hip_runtime.h>

// AttentionNet N=128, a1=a2=64, f=2 — R8: R6 structure (best so far: fused
// single launch, grid 2N=256, 2 blocks per n, m-exchange via encoded global
// slots) + pairwise-rcp inner loop:
//   1/(1+a) + 1/(1+b) = (u0+u1)/(u0*u1), u = 1+x  ->  one v_rcp per TWO
// sigmoids. Per k-pair per row: 2 readlane + 2 fma + add + mul + rcp + fma.

constexpr int A   = 64;
constexpr int PAD = 65;
constexpr float L2E  = 1.4426950408889634f;
constexpr float EPSF = 1e-6f;

__device__ __forceinline__ float bcast(float v, int srcLane) {
    return __int_as_float(__builtin_amdgcn_readlane(__float_as_int(v), srcLane));
}
__device__ __forceinline__ float rcpf(float v) { return __builtin_amdgcn_rcpf(v); }
__device__ __forceinline__ float ex2(float v)  { return __builtin_amdgcn_exp2f(v); }

// Reduce rows row0,row0+1 (lane <-> column j). lane0 writes LDS mbuf and the
// encoded global slot (m+2.0: sign 0, exp 128 -> self-validating vs poison).
__device__ __forceinline__ void att2q(const float* __restrict__ prow,
                                      const float* __restrict__ qL,
                                      int row0, int lane,
                                      float* __restrict__ mbuf,
                                      float* __restrict__ mg)   // [64] this n,stage
{
    const float qreg0 = qL[row0 * PAD + lane];          // conflict-free row reads
    const float qreg1 = qL[(row0 + 1) * PAD + lane];
    float acc0 = 0.f, acc1 = 0.f;
#pragma unroll 1
    for (int c = 0; c < 4; ++c) {
        float pk[16];
#pragma unroll
        for (int t = 0; t < 16; ++t) pk[t] = prow[c * 16 + t];
#pragma unroll
        for (int t = 0; t < 8; ++t) {                   // k-pairs
            const int k0 = c * 16 + 2 * t, k1 = k0 + 1;
            // row 0
            {
                float u0 = fmaf(pk[2 * t],     bcast(qreg0, k0), 1.0f);
                float u1 = fmaf(pk[2 * t + 1], bcast(qreg0, k1), 1.0f);
                acc0 = fmaf(u0 + u1, rcpf(u0 * u1), acc0);
            }
            // row 1
            {
                float u0 = fmaf(pk[2 * t],     bcast(qreg1, k0), 1.0f);
                float u1 = fmaf(pk[2 * t + 1], bcast(qreg1, k1), 1.0f);
                acc1 = fmaf(u0 + u1, rcpf(u0 * u1), acc1);
            }
        }
    }
    float s0 = acc0, m0 = acc0, s1 = acc1, m1 = acc1;
#pragma unroll
    for (int off = 1; off < 64; off <<= 1) {
        s0 += __shfl_xor(s0, off, 64);
        m0 = fmaxf(m0, __shfl_xor(m0, off, 64));
        s1 += __shfl_xor(s1, off, 64);
        m1 = fmaxf(m1, __shfl_xor(m1, off, 64));
    }
    if (lane == 0) {
        // acc = 64*c: mean_j c = s/4096, max_j c = m/64.
        float v0 = (s0 * (1.0f / 4096.0f)) / (m0 * (1.0f / 64.0f) + EPSF);
        float v1 = (s1 * (1.0f / 4096.0f)) / (m1 * (1.0f / 64.0f) + EPSF);
        mbuf[row0]     = v0;
        mbuf[row0 + 1] = v1;
        __hip_atomic_store(mg + row0,     v0 + 2.0f, __ATOMIC_RELAXED, __HIP_MEMORY_SCOPE_AGENT);
        __hip_atomic_store(mg + row0 + 1, v1 + 2.0f, __ATOMIC_RELAXED, __HIP_MEMORY_SCOPE_AGENT);
    }
}

__device__ __forceinline__ float softmax64(float m, float sharp, float th, bool last)
{
    float v = fmaxf(0.f, m * sharp + th);
    float mx = v;
#pragma unroll
    for (int off = 1; off < 64; off <<= 1) mx = fmaxf(mx, __shfl_xor(mx, off, 64));
    float e = __expf(v - mx);
    float s = e;
#pragma unroll
    for (int off = 1; off < 64; off <<= 1) s += __shfl_xor(s, off, 64);
    float r = e / s;
    if (!last) {
        float rm = r;
#pragma unroll
        for (int off = 1; off < 64; off <<= 1) rm = fmaxf(rm, __shfl_xor(rm, off, 64));
        r = r / (rm + EPSF);
    }
    return r;
}

// Wave-0 only: own half's m from LDS, peer half via spin on encoded slots.
__device__ __forceinline__ float exch_soft(const float* __restrict__ mbuf,
                                           const float* __restrict__ mg,
                                           int half, int lane,
                                           float sharp, float th, bool last)
{
    float mv;
    if ((lane >> 5) == half) {
        mv = mbuf[lane];
    } else {
        const float* p = mg + lane;
        for (;;) {
            float f = __hip_atomic_load(p, __ATOMIC_RELAXED, __HIP_MEMORY_SCOPE_AGENT);
            unsigned u = __float_as_uint(f);
            if ((u >> 23) == 0x80u) { mv = f - 2.0f; break; }   // sign 0, exp 128
            __builtin_amdgcn_s_sleep(1);
        }
    }
    return softmax64(mv, sharp, th, last);
}

__global__ __launch_bounds__(1024, 2)
void attn_half(const float* __restrict__ x,
               const float* __restrict__ fcW, const float* __restrict__ fcb,
               const float* __restrict__ p1W, const float* __restrict__ p1b,
               const float* __restrict__ p1s, const float* __restrict__ p1t,
               const float* __restrict__ p2W, const float* __restrict__ p2b,
               const float* __restrict__ p2s, const float* __restrict__ p2t,
               const float* __restrict__ oW,  const float* __restrict__ ob,
               const float* __restrict__ os,  const float* __restrict__ ot,
               float* __restrict__ mglob,     // [N][3][64]
               float* __restrict__ out)
{
    __shared__ float pL[A * PAD];
    __shared__ float qL[A * PAD];
    __shared__ float mbuf[A];
    __shared__ float v1buf[A], v2buf[A];

    const int tid = threadIdx.x, lane = tid & 63, wv = tid >> 6;
    const int n = blockIdx.x >> 1, half = blockIdx.x & 1;
    const int row0 = half * 32 + wv * 2;
    const int i = tid >> 4, j = (tid & 15) * 4;
    float* mg = mglob + (size_t)n * 3 * A;

    // ---- x loaded once; h0/h1 live in registers ----
    const float4* x0v = (const float4*)(x + (size_t)n * 2 * A * A);
    const float4* x1v = x0v + (A * A / 4);
    const float4 a = x0v[tid];
    const float4 c = x1v[tid];
    const float w00 = fcW[0], w01 = fcW[1], w10 = fcW[2], w11 = fcW[3];
    const float b0 = fcb[0], b1 = fcb[1];
    const float h0v[4] = { fmaxf(0.f, w00 * a.x + w01 * c.x + b0),
                           fmaxf(0.f, w00 * a.y + w01 * c.y + b0),
                           fmaxf(0.f, w00 * a.z + w01 * c.z + b0),
                           fmaxf(0.f, w00 * a.w + w01 * c.w + b0) };
    const float h1v[4] = { fmaxf(0.f, w10 * a.x + w11 * c.x + b1),
                           fmaxf(0.f, w10 * a.y + w11 * c.y + b1),
                           fmaxf(0.f, w10 * a.z + w11 * c.z + b1),
                           fmaxf(0.f, w10 * a.w + w11 * c.w + b1) };

    // ======== stage B: X = h0 (row-major) ========
    {
        const float W0 = p1W[0], W1 = p1W[1], bb = p1b[0];
#pragma unroll
        for (int t = 0; t < 4; ++t) {
            pL[i * PAD + j + t] = ex2(-L2E * (W0 * h0v[t] + bb));
            qL[i * PAD + j + t] = ex2(-L2E * (W1 * h0v[t]));
        }
    }
    __syncthreads();
    att2q(pL + lane * PAD, qL, row0, lane, mbuf, mg);
    __syncthreads();
    if (wv == 0) v1buf[lane] = exch_soft(mbuf, mg, half, lane, p1s[0], p1t[0], false);
    __syncthreads();

    // ======== stage C: X[r][k] = h1[k][r] * v1[k] (transposed store) ========
    {
        const float W0 = p2W[0], W1 = p2W[1], bb = p2b[0];
        const float sc = v1buf[i];
#pragma unroll
        for (int t = 0; t < 4; ++t) {
            float hv = h1v[t] * sc;
            pL[(j + t) * PAD + i] = ex2(-L2E * (W0 * hv + bb));
            qL[(j + t) * PAD + i] = ex2(-L2E * (W1 * hv));
        }
    }
    __syncthreads();
    att2q(pL + lane * PAD, qL, row0, lane, mbuf, mg + A);
    __syncthreads();
    if (wv == 0) v2buf[lane] = exch_soft(mbuf, mg + A, half, lane, p2s[0], p2t[0], false);
    __syncthreads();

    // ======== stage D: X = h0 * v1[i] * v2[j] (row-major) ========
    {
        const float W0 = oW[0], W1 = oW[1], bb = ob[0];
        const float sc = v1buf[i];
        const float4 v2q = *(const float4*)&v2buf[j];
        const float v2a[4] = { v2q.x, v2q.y, v2q.z, v2q.w };
#pragma unroll
        for (int t = 0; t < 4; ++t) {
            float hv = h0v[t] * sc * v2a[t];
            pL[i * PAD + j + t] = ex2(-L2E * (W0 * hv + bb));
            qL[i * PAD + j + t] = ex2(-L2E * (W1 * hv));
        }
    }
    __syncthreads();
    att2q(pL + lane * PAD, qL, row0, lane, mbuf, mg + 2 * A);
    __syncthreads();

    // ======== final softmax (is_last); each block writes its 32 outputs ====
    if (wv == 0) {
        float r = exch_soft(mbuf, mg + 2 * A, half, lane, os[0], ot[0], true);
        if ((lane >> 5) == half) out[(size_t)n * A + lane] = r;
    }
}

extern "C" void kernel_launch(void* const* d_in, const int* in_sizes, int n_in,
                              void* d_out, int out_size, void* d_ws, size_t ws_size,
                              hipStream_t stream)
{
    (void)n_in; (void)out_size; (void)ws_size;
    const float* x   = (const float*)d_in[0];
    const float* fcW = (const float*)d_in[1];
    const float* fcb = (const float*)d_in[2];
    const float* p1W = (const float*)d_in[3];
    const float* p1b = (const float*)d_in[4];
    const float* p1s = (const float*)d_in[5];
    const float* p1t = (const float*)d_in[6];
    const float* p2W = (const float*)d_in[7];
    const float* p2b = (const float*)d_in[8];
    const float* p2s = (const float*)d_in[9];
    const float* p2t = (const float*)d_in[10];
    const float* oW  = (const float*)d_in[11];
    const float* ob  = (const float*)d_in[12];
    const float* os  = (const float*)d_in[13];
    const float* ot  = (const float*)d_in[14];
    float* out = (float*)d_out;

    const int N = in_sizes[0] / (2 * A * A);   // 128
    float* mglob = (float*)d_ws;               // [N][3][64]

    attn_half<<<2 * N, 1024, 0, stream>>>(x, fcW, fcb,
                                          p1W, p1b, p1s, p1t,
                                          p2W, p2b, p2s, p2t,
                                          oW, ob, os, ot, mglob, out);
}

// Round 10
// 102.275 us; speedup vs baseline: 1.0470x; 1.0137x over previous
//
#include <hip/hip_runtime.h>

// AttentionNet N=128, a1=a2=64, f=2 — R10 (= R9 with DPP ctrl as template
// constant): fused single launch, grid 2N=256, 2 blocks per n, encoded-global
// m-exchange, pairwise-rcp math, DS pipe decongested:
//   * PAD 68 (272B stride, 16B aligned) -> p-loads are ds_read_b128
//   * wave reductions via DPP (VALU pipe) instead of ds_bpermute (DS pipe)
//   * p/q preamble stores as float4 where layout permits

constexpr int A   = 64;
constexpr int PAD = 68;   // floats; 272 B row stride: 16B-aligned
constexpr float L2E  = 1.4426950408889634f;
constexpr float EPSF = 1e-6f;

__device__ __forceinline__ float bcast(float v, int srcLane) {
    return __int_as_float(__builtin_amdgcn_readlane(__float_as_int(v), srcLane));
}
__device__ __forceinline__ float rcpf(float v) { return __builtin_amdgcn_rcpf(v); }
__device__ __forceinline__ float ex2(float v)  { return __builtin_amdgcn_exp2f(v); }

// DPP helpers: full-wave64 sum/max on the VALU pipe (no DS ops).
// bound_ctrl=true -> out-of-range sources read 0; identity 0 is valid for the
// non-negative values reduced here.
template <int CTRL>
__device__ __forceinline__ float upd_dpp(float src) {
    return __int_as_float(__builtin_amdgcn_update_dpp(
        0, __float_as_int(src), CTRL, 0xF, 0xF, true));
}
__device__ __forceinline__ float wave_sum64(float x) {
    x += upd_dpp<0x111>(x);   // row_shr:1
    x += upd_dpp<0x112>(x);   // row_shr:2
    x += upd_dpp<0x114>(x);   // row_shr:4
    x += upd_dpp<0x118>(x);   // row_shr:8
    x += upd_dpp<0x142>(x);   // row_bcast:15
    x += upd_dpp<0x143>(x);   // row_bcast:31
    return bcast(x, 63);
}
__device__ __forceinline__ float wave_max64(float x) {   // x >= 0 required
    x = fmaxf(x, upd_dpp<0x111>(x));
    x = fmaxf(x, upd_dpp<0x112>(x));
    x = fmaxf(x, upd_dpp<0x114>(x));
    x = fmaxf(x, upd_dpp<0x118>(x));
    x = fmaxf(x, upd_dpp<0x142>(x));
    x = fmaxf(x, upd_dpp<0x143>(x));
    return bcast(x, 63);
}

// Reduce rows row0,row0+1 (lane <-> column j). lane0 writes LDS mbuf and the
// encoded global slot (m+2.0: sign 0, exp 128 -> self-validating vs poison).
__device__ __forceinline__ void att2q(const float* __restrict__ prow,
                                      const float* __restrict__ qL,
                                      int row0, int lane,
                                      float* __restrict__ mbuf,
                                      float* __restrict__ mg)
{
    const float qreg0 = qL[row0 * PAD + lane];
    const float qreg1 = qL[(row0 + 1) * PAD + lane];
    float acc0 = 0.f, acc1 = 0.f;
#pragma unroll 1
    for (int c = 0; c < 4; ++c) {
        float pk[16];                                    // 4x ds_read_b128
        *(float4*)(&pk[0])  = *(const float4*)(prow + c * 16 + 0);
        *(float4*)(&pk[4])  = *(const float4*)(prow + c * 16 + 4);
        *(float4*)(&pk[8])  = *(const float4*)(prow + c * 16 + 8);
        *(float4*)(&pk[12]) = *(const float4*)(prow + c * 16 + 12);
#pragma unroll
        for (int t = 0; t < 8; ++t) {                    // k-pairs, pairwise rcp
            const int k0 = c * 16 + 2 * t, k1 = k0 + 1;
            {
                float u0 = fmaf(pk[2 * t],     bcast(qreg0, k0), 1.0f);
                float u1 = fmaf(pk[2 * t + 1], bcast(qreg0, k1), 1.0f);
                acc0 = fmaf(u0 + u1, rcpf(u0 * u1), acc0);
            }
            {
                float u0 = fmaf(pk[2 * t],     bcast(qreg1, k0), 1.0f);
                float u1 = fmaf(pk[2 * t + 1], bcast(qreg1, k1), 1.0f);
                acc1 = fmaf(u0 + u1, rcpf(u0 * u1), acc1);
            }
        }
    }
    const float s0 = wave_sum64(acc0), m0 = wave_max64(acc0);
    const float s1 = wave_sum64(acc1), m1 = wave_max64(acc1);
    if (lane == 0) {
        // acc = 64*c: mean_j c = s/4096, max_j c = m/64.
        float v0 = (s0 * (1.0f / 4096.0f)) / (m0 * (1.0f / 64.0f) + EPSF);
        float v1 = (s1 * (1.0f / 4096.0f)) / (m1 * (1.0f / 64.0f) + EPSF);
        mbuf[row0]     = v0;
        mbuf[row0 + 1] = v1;
        __hip_atomic_store(mg + row0,     v0 + 2.0f, __ATOMIC_RELAXED, __HIP_MEMORY_SCOPE_AGENT);
        __hip_atomic_store(mg + row0 + 1, v1 + 2.0f, __ATOMIC_RELAXED, __HIP_MEMORY_SCOPE_AGENT);
    }
}

__device__ __forceinline__ float softmax64(float m, float sharp, float th, bool last)
{
    float v = fmaxf(0.f, m * sharp + th);        // >= 0
    float mx = wave_max64(v);
    float e = __expf(v - mx);                    // > 0
    float s = wave_sum64(e);
    float r = e / s;                             // > 0
    if (!last) {
        float rm = wave_max64(r);
        r = r / (rm + EPSF);
    }
    return r;
}

// Wave-0 only: own half's m from LDS, peer half via spin on encoded slots.
__device__ __forceinline__ float exch_soft(const float* __restrict__ mbuf,
                                           const float* __restrict__ mg,
                                           int half, int lane,
                                           float sharp, float th, bool last)
{
    float mv;
    if ((lane >> 5) == half) {
        mv = mbuf[lane];
    } else {
        const float* p = mg + lane;
        for (;;) {
            float f = __hip_atomic_load(p, __ATOMIC_RELAXED, __HIP_MEMORY_SCOPE_AGENT);
            unsigned u = __float_as_uint(f);
            if ((u >> 23) == 0x80u) { mv = f - 2.0f; break; }   // sign 0, exp 128
            __builtin_amdgcn_s_sleep(1);
        }
    }
    return softmax64(mv, sharp, th, last);
}

__global__ __launch_bounds__(1024, 2)
void attn_half(const float* __restrict__ x,
               const float* __restrict__ fcW, const float* __restrict__ fcb,
               const float* __restrict__ p1W, const float* __restrict__ p1b,
               const float* __restrict__ p1s, const float* __restrict__ p1t,
               const float* __restrict__ p2W, const float* __restrict__ p2b,
               const float* __restrict__ p2s, const float* __restrict__ p2t,
               const float* __restrict__ oW,  const float* __restrict__ ob,
               const float* __restrict__ os,  const float* __restrict__ ot,
               float* __restrict__ mglob,     // [N][3][64]
               float* __restrict__ out)
{
    __shared__ __align__(16) float pL[A * PAD];
    __shared__ __align__(16) float qL[A * PAD];
    __shared__ float mbuf[A];
    __shared__ float v1buf[A], v2buf[A];

    const int tid = threadIdx.x, lane = tid & 63, wv = tid >> 6;
    const int n = blockIdx.x >> 1, half = blockIdx.x & 1;
    const int row0 = half * 32 + wv * 2;
    const int i = tid >> 4, j = (tid & 15) * 4;
    float* mg = mglob + (size_t)n * 3 * A;

    // ---- x loaded once; h0/h1 live in registers ----
    const float4* x0v = (const float4*)(x + (size_t)n * 2 * A * A);
    const float4* x1v = x0v + (A * A / 4);
    const float4 a = x0v[tid];
    const float4 c = x1v[tid];
    const float w00 = fcW[0], w01 = fcW[1], w10 = fcW[2], w11 = fcW[3];
    const float b0 = fcb[0], b1 = fcb[1];
    const float h0v[4] = { fmaxf(0.f, w00 * a.x + w01 * c.x + b0),
                           fmaxf(0.f, w00 * a.y + w01 * c.y + b0),
                           fmaxf(0.f, w00 * a.z + w01 * c.z + b0),
                           fmaxf(0.f, w00 * a.w + w01 * c.w + b0) };
    const float h1v[4] = { fmaxf(0.f, w10 * a.x + w11 * c.x + b1),
                           fmaxf(0.f, w10 * a.y + w11 * c.y + b1),
                           fmaxf(0.f, w10 * a.z + w11 * c.z + b1),
                           fmaxf(0.f, w10 * a.w + w11 * c.w + b1) };

    // ======== stage B: X = h0 (row-major, float4 stores) ========
    {
        const float W0 = p1W[0], W1 = p1W[1], bb = p1b[0];
        float4 pv, qv;
        pv.x = ex2(-L2E * (W0 * h0v[0] + bb)); qv.x = ex2(-L2E * (W1 * h0v[0]));
        pv.y = ex2(-L2E * (W0 * h0v[1] + bb)); qv.y = ex2(-L2E * (W1 * h0v[1]));
        pv.z = ex2(-L2E * (W0 * h0v[2] + bb)); qv.z = ex2(-L2E * (W1 * h0v[2]));
        pv.w = ex2(-L2E * (W0 * h0v[3] + bb)); qv.w = ex2(-L2E * (W1 * h0v[3]));
        *(float4*)&pL[i * PAD + j] = pv;
        *(float4*)&qL[i * PAD + j] = qv;
    }
    __syncthreads();
    att2q(pL + lane * PAD, qL, row0, lane, mbuf, mg);
    __syncthreads();
    if (wv == 0) v1buf[lane] = exch_soft(mbuf, mg, half, lane, p1s[0], p1t[0], false);
    __syncthreads();

    // ======== stage C: X[r][k] = h1[k][r] * v1[k] (transposed scalar stores) ====
    {
        const float W0 = p2W[0], W1 = p2W[1], bb = p2b[0];
        const float sc = v1buf[i];
#pragma unroll
        for (int t = 0; t < 4; ++t) {
            float hv = h1v[t] * sc;
            pL[(j + t) * PAD + i] = ex2(-L2E * (W0 * hv + bb));
            qL[(j + t) * PAD + i] = ex2(-L2E * (W1 * hv));
        }
    }
    __syncthreads();
    att2q(pL + lane * PAD, qL, row0, lane, mbuf, mg + A);
    __syncthreads();
    if (wv == 0) v2buf[lane] = exch_soft(mbuf, mg + A, half, lane, p2s[0], p2t[0], false);
    __syncthreads();

    // ======== stage D: X = h0 * v1[i] * v2[j] (row-major, float4 stores) ====
    {
        const float W0 = oW[0], W1 = oW[1], bb = ob[0];
        const float sc = v1buf[i];
        const float4 v2q = *(const float4*)&v2buf[j];
        float hv0 = h0v[0] * sc * v2q.x, hv1 = h0v[1] * sc * v2q.y;
        float hv2 = h0v[2] * sc * v2q.z, hv3 = h0v[3] * sc * v2q.w;
        float4 pv, qv;
        pv.x = ex2(-L2E * (W0 * hv0 + bb)); qv.x = ex2(-L2E * (W1 * hv0));
        pv.y = ex2(-L2E * (W0 * hv1 + bb)); qv.y = ex2(-L2E * (W1 * hv1));
        pv.z = ex2(-L2E * (W0 * hv2 + bb)); qv.z = ex2(-L2E * (W1 * hv2));
        pv.w = ex2(-L2E * (W0 * hv3 + bb)); qv.w = ex2(-L2E * (W1 * hv3));
        *(float4*)&pL[i * PAD + j] = pv;
        *(float4*)&qL[i * PAD + j] = qv;
    }
    __syncthreads();
    att2q(pL + lane * PAD, qL, row0, lane, mbuf, mg + 2 * A);
    __syncthreads();

    // ======== final softmax (is_last); each block writes its 32 outputs ====
    if (wv == 0) {
        float r = exch_soft(mbuf, mg + 2 * A, half, lane, os[0], ot[0], true);
        if ((lane >> 5) == half) out[(size_t)n * A + lane] = r;
    }
}

extern "C" void kernel_launch(void* const* d_in, const int* in_sizes, int n_in,
                              void* d_out, int out_size, void* d_ws, size_t ws_size,
                              hipStream_t stream)
{
    (void)n_in; (void)out_size; (void)ws_size;
    const float* x   = (const float*)d_in[0];
    const float* fcW = (const float*)d_in[1];
    const float* fcb = (const float*)d_in[2];
    const float* p1W = (const float*)d_in[3];
    const float* p1b = (const float*)d_in[4];
    const float* p1s = (const float*)d_in[5];
    const float* p1t = (const float*)d_in[6];
    const float* p2W = (const float*)d_in[7];
    const float* p2b = (const float*)d_in[8];
    const float* p2s = (const float*)d_in[9];
    const float* p2t = (const float*)d_in[10];
    const float* oW  = (const float*)d_in[11];
    const float* ob  = (const float*)d_in[12];
    const float* os  = (const float*)d_in[13];
    const float* ot  = (const float*)d_in[14];
    float* out = (float*)d_out;

    const int N = in_sizes[0] / (2 * A * A);   // 128
    float* mglob = (float*)d_ws;               // [N][3][64]

    attn_half<<<2 * N, 1024, 0, stream>>>(x, fcW, fcb,
                                          p1W, p1b, p1s, p1t,
                                          p2W, p2b, p2s, p2t,
                                          oW, ob, os, ot, mglob, out);
}